// Round 23
// baseline (231.981 us; speedup 1.0000x reference)
//
#include <hip/hip_runtime.h>
#include <hip/hip_bf16.h>
#include <cstdint>

#define NC 28
#define HW 65536   // 256*256
#define ROWW 256
#define COLW 310
#define BATCH 16

typedef __hip_bfloat16 bf16;
typedef _Float16 h2v __attribute__((ext_vector_type(2)));

__device__ __forceinline__ unsigned int pkh(float lo, float hi) {
    auto h = __builtin_amdgcn_cvt_pkrtz(lo, hi);
    return __builtin_bit_cast(unsigned int, h);
}
__device__ __forceinline__ h2v u2h(unsigned int u) { return __builtin_bit_cast(h2v, u); }
__device__ __forceinline__ unsigned int h2u(h2v h) { return __builtin_bit_cast(unsigned int, h); }
__device__ __forceinline__ float h2f_lo(unsigned int u) {
    return (float)__builtin_bit_cast(_Float16, (unsigned short)(u & 0xffffu));
}
__device__ __forceinline__ float h2f_hi(unsigned int u) {
    return (float)__builtin_bit_cast(_Float16, (unsigned short)(u >> 16));
}
// forced async global loads (compiler cannot sink an asm volatile)
__device__ __forceinline__ void gl_f32x2(float2& d, const float* p) {
    asm volatile("global_load_dwordx2 %0, %1, off" : "=v"(d) : "v"(p));
}
__device__ __forceinline__ void gl_b32(unsigned int& d, const unsigned short* p) {
    asm volatile("global_load_dword %0, %1, off" : "=v"(d) : "v"(p));
}
__device__ __forceinline__ void wait_vm0() {
    asm volatile("s_waitcnt vmcnt(0)" ::: "memory");
    __builtin_amdgcn_sched_barrier(0);   // rule #18
}

#define REP28A(X) X(0) X(1) X(2) X(3) X(4) X(5) X(6) X(7) X(8) X(9) X(10) X(11) X(12) X(13) \
                  X(14) X(15) X(16) X(17) X(18) X(19) X(20) X(21) X(22) X(23) X(24) X(25) X(26) X(27)

// Intermediates use [b][h][c][w] layout: elem index = ((b*256+h)*28+c)*256 + w
// hdr layout (uint words): as before
#define HDR_BYTES 16384

// ---------------- K0: prep ----------------
__global__ void k0_prep(const float* __restrict__ w1mm, const float* __restrict__ w1pv,
                        const float* __restrict__ w2mm, const float* __restrict__ w2pv,
                        const float* __restrict__ b1mm, const float* __restrict__ b1pv,
                        const float* __restrict__ b2mm, const float* __restrict__ b2pv,
                        const float* __restrict__ dwm,  const float* __restrict__ dwp,
                        const float* __restrict__ dbm,  const float* __restrict__ dbp,
                        unsigned int* __restrict__ hdr)
{
    int t = threadIdx.x;
    for (int e = t; e < 784; e += 256) {
        int c = e / 28, o = e - c * 28;
        hdr[e]       = pkh(w1mm[o * 28 + c], w1pv[o * 28 + c]);
        hdr[784 + e] = pkh(w2mm[e], w2pv[e]);
    }
    if (t < 28) {
        hdr[1568 + t] = pkh(b1mm[t], b1pv[t]);
        hdr[1596 + t] = pkh(b2mm[t], b2pv[t]);
        hdr[2324 + t] = pkh(dbm[t], dbp[t]);
    }
    for (int e = t; e < 700; e += 256)
        hdr[1624 + e] = pkh(dwm[e], dwp[e]);
    float* alpha = (float*)(hdr + 2352);
    for (int col = t; col < COLW; col += 256) {
        int imin = (col > 255) ? ((col - 254) >> 1) : 0;
        int imax = min(27, col >> 1);
        alpha[col] = 1.0f / (float)(imax - imin + 1);
    }
}

// ---------------- K1: conv1x1 x2; native h2v FMA, 9-slot rotating dwordx2 prefetch ----------------
__global__ __launch_bounds__(256, 4) void k1_conv1x1(
    const float* __restrict__ Phi, const unsigned int* __restrict__ hdr,
    unsigned int* __restrict__ t_pk, unsigned int* __restrict__ m1_pk)
{
    int idx = blockIdx.x * 256 + threadIdx.x;   // pixel-pair index
    int b   = idx >> 15;                        // 32768 pairs per batch
    int hw2 = (idx & 32767) << 1;
    const float* phi = Phi + (size_t)b * NC * HW + hw2;
    const unsigned int* w1h = hdr;              // [c*28+o]
    const unsigned int* w2h = hdr + 784;        // [o*28+m]
    const unsigned int* b1h = hdr + 1568;
    const unsigned int* b2h = hdr + 1596;

#define DECL_M(i) h2v MA##i = u2h(b1h[i]), MB##i = MA##i;
    REP28A(DECL_M)
#undef DECL_M

    float2 PQ0, PQ1, PQ2, PQ3, PQ4, PQ5, PQ6, PQ7, PQ8;
#define GLX2(D, C) asm volatile("global_load_dwordx2 %0, %1, off" : "=v"(D) : "v"(phi + (size_t)(C) * HW))
#define VMW(N) do { asm volatile("s_waitcnt vmcnt(" #N ")" ::: "memory"); \
                    __builtin_amdgcn_sched_barrier(0); } while(0)
#define FMA_M(i) MA##i = wr1_[i] * pa + MA##i; MB##i = wr1_[i] * pb + MB##i;
#define K1CONS(C, S) do { \
    h2v pa = u2h(pkh(PQ##S.x, PQ##S.x)); \
    h2v pb = u2h(pkh(PQ##S.y, PQ##S.y)); \
    const h2v* wr1_ = (const h2v*)(w1h + (C) * NC); \
    REP28A(FMA_M) \
} while(0)

    GLX2(PQ0, 0); GLX2(PQ1, 1); GLX2(PQ2, 2); GLX2(PQ3, 3);
    GLX2(PQ4, 4); GLX2(PQ5, 5); GLX2(PQ6, 6); GLX2(PQ7, 7);
    GLX2(PQ8, 8);  VMW(8); K1CONS(0, 0);
    GLX2(PQ0, 9);  VMW(8); K1CONS(1, 1);
    GLX2(PQ1, 10); VMW(8); K1CONS(2, 2);
    GLX2(PQ2, 11); VMW(8); K1CONS(3, 3);
    GLX2(PQ3, 12); VMW(8); K1CONS(4, 4);
    GLX2(PQ4, 13); VMW(8); K1CONS(5, 5);
    GLX2(PQ5, 14); VMW(8); K1CONS(6, 6);
    GLX2(PQ6, 15); VMW(8); K1CONS(7, 7);
    GLX2(PQ7, 16); VMW(8); K1CONS(8, 8);
    GLX2(PQ8, 17); VMW(8); K1CONS(9, 0);
    GLX2(PQ0, 18); VMW(8); K1CONS(10, 1);
    GLX2(PQ1, 19); VMW(8); K1CONS(11, 2);
    GLX2(PQ2, 20); VMW(8); K1CONS(12, 3);
    GLX2(PQ3, 21); VMW(8); K1CONS(13, 4);
    GLX2(PQ4, 22); VMW(8); K1CONS(14, 5);
    GLX2(PQ5, 23); VMW(8); K1CONS(15, 6);
    GLX2(PQ6, 24); VMW(8); K1CONS(16, 7);
    GLX2(PQ7, 25); VMW(8); K1CONS(17, 8);
    GLX2(PQ8, 26); VMW(8); K1CONS(18, 0);
    GLX2(PQ0, 27); VMW(8); K1CONS(19, 1);
    VMW(7); K1CONS(20, 2);
    VMW(6); K1CONS(21, 3);
    VMW(5); K1CONS(22, 4);
    VMW(4); K1CONS(23, 5);
    VMW(3); K1CONS(24, 6);
    VMW(2); K1CONS(25, 7);
    VMW(1); K1CONS(26, 8);
    VMW(0); K1CONS(27, 0);
#undef K1CONS
#undef FMA_M
#undef VMW
#undef GLX2

    // [b][h][c][w] layout: 28 stores span 28 KB instead of 7 MB
    int h = hw2 >> 8, wcol = hw2 & 255;
    size_t ibase = ((size_t)(b * 256 + h) * 28) << 8;   // + (c<<8) + w
#define ST_M(i) *reinterpret_cast<uint2*>(m1_pk + ibase + ((i) << 8) + wcol) = \
    make_uint2(h2u(MA##i), h2u(MB##i));
    REP28A(ST_M)
#undef ST_M

    for (int o = 0; o < NC; o++) {
        const h2v* wr2_ = (const h2v*)(w2h + o * NC);
        h2v Ta = u2h(b2h[o]), Tb = Ta;
#define FMA_T(i) Ta = wr2_[i] * MA##i + Ta; Tb = wr2_[i] * MB##i + Tb;
        REP28A(FMA_T)
#undef FMA_T
        *reinterpret_cast<uint2*>(t_pk + ibase + (o << 8) + wcol) = make_uint2(h2u(Ta), h2u(Tb));
    }
}

// ---------------- K2: dwconv5 + sigmoid + emb + where; [h][c][w] layout ----------------
#define TR 16
#define LROW 264   // words per LDS row; interior at [4..259], pads [2,3] and [260,261]

#define RB(GR) ((((size_t)(b * 256 + (GR)) * 28 + c)) << 8)   // row base elem index

#define LDROW(S, LR) do { \
    const uint2* rp_ = reinterpret_cast<const uint2*>(&st[(LR) * LROW + 2 + cc]); \
    uint2 a_ = rp_[0], b_ = rp_[1], c_ = rp_[2]; \
    W##S##0 = u2h(a_.x); W##S##1 = u2h(a_.y); W##S##2 = u2h(b_.x); \
    W##S##3 = u2h(b_.y); W##S##4 = u2h(c_.x); W##S##5 = u2h(c_.y); \
} while(0)

#define PRE(S, R) do { \
    mu##S = *reinterpret_cast<const uint2*>(m1_pk + RB(h0 + (R)) + cc); \
} while(0)

#define TAPR(S, B) \
    acc0 = wqh[(B)+0] * W##S##0 + acc0; acc1 = wqh[(B)+0] * W##S##1 + acc1; \
    acc0 = wqh[(B)+1] * W##S##1 + acc0; acc1 = wqh[(B)+1] * W##S##2 + acc1; \
    acc0 = wqh[(B)+2] * W##S##2 + acc0; acc1 = wqh[(B)+2] * W##S##3 + acc1; \
    acc0 = wqh[(B)+3] * W##S##3 + acc0; acc1 = wqh[(B)+3] * W##S##4 + acc1; \
    acc0 = wqh[(B)+4] * W##S##4 + acc0; acc1 = wqh[(B)+4] * W##S##5 + acc1;

#define CROW2(R, PS, S0,S1,S2,S3,S4) do { \
    h2v acc0 = dbch, acc1 = dbch; \
    TAPR(S0, 0) TAPR(S1, 5) TAPR(S2, 10) TAPR(S3, 15) TAPR(S4, 20) \
    float am0 = (float)acc0.x, ap0 = (float)acc0.y; \
    float am1 = (float)acc1.x, ap1 = (float)acc1.y; \
    float atm0 = __builtin_amdgcn_rcpf(1.f + __expf(-am0)); \
    float atp0 = __builtin_amdgcn_rcpf(1.f + __expf(-ap0)); \
    float atm1 = __builtin_amdgcn_rcpf(1.f + __expf(-am1)); \
    float atp1 = __builtin_amdgcn_rcpf(1.f + __expf(-ap1)); \
    float m1m0 = h2f_lo(mu##PS.x), m1p0 = h2f_hi(mu##PS.x); \
    float m1m1 = h2f_lo(mu##PS.y), m1p1 = h2f_hi(mu##PS.y); \
    float em0 = fmaf(m1m0, atm0, m1m0); \
    float ep0 = fmaf(m1p0, atp0, m1p0); \
    float em1 = fmaf(m1m1, atm1, m1m1); \
    float ep1 = fmaf(m1p1, atp1, m1p1); \
    if (em0 == 0.f) em0 = 1e-6f; \
    if (ep0 == 0.f) ep0 = 1e-6f; \
    if (em1 == 0.f) em1 = 1e-6f; \
    if (ep1 == 0.f) ep1 = 1e-6f; \
    size_t off_ = RB(h0 + (R)) + cc; \
    *reinterpret_cast<unsigned int*>(phm + off_) = pkh(em0, em1); \
    *reinterpret_cast<unsigned int*>(php + off_) = pkh(ep0, ep1); \
} while(0)

__global__ __launch_bounds__(256, 4) void k2_attn(
    const unsigned int* __restrict__ t_pk, const unsigned int* __restrict__ m1_pk,
    const unsigned int* __restrict__ hdr,
    unsigned short* __restrict__ phm, unsigned short* __restrict__ php)
{
    __shared__ unsigned int st[(TR + 4) * LROW];   // 21,120 B

    int bid = blockIdx.x;
    int rt = bid & 15;
    int c  = (bid >> 4) % NC;
    int b  = (bid >> 4) / NC;
    int r0 = rt * TR;
    int tid = threadIdx.x;
    int lane = tid & 63;
    int wv = tid >> 6;
    int cc = (tid & 127) * 2;        // column pair base
    int half = tid >> 7;             // 0: rows 0..7, 1: rows 8..15
    int lbase = half * 8;
    int h0 = r0 + lbase;

    if (tid < 80) {
        int rr = tid >> 2, jj = tid & 3;
        st[rr * LROW + ((jj < 2) ? 2 + jj : 258 + jj)] = 0u;
    }

#pragma unroll
    for (int j = 0; j < 5; j++) {
        int r = wv * 5 + j;
        int gr = r0 - 2 + r;
        if (gr >= 0 && gr < 256) {
            const unsigned int* gsrc = t_pk + RB(gr) + lane * 4;
            __builtin_amdgcn_global_load_lds(
                (const __attribute__((address_space(1))) unsigned int*)gsrc,
                (__attribute__((address_space(3))) unsigned int*)&st[r * LROW + 4],
                16, 0, 0);
        } else {
            st[r * LROW + 4 + lane]       = 0u;
            st[r * LROW + 4 + 64 + lane]  = 0u;
            st[r * LROW + 4 + 128 + lane] = 0u;
            st[r * LROW + 4 + 192 + lane] = 0u;
        }
    }

    h2v wqh[25];
#pragma unroll
    for (int k = 0; k < 25; k++)
        wqh[k] = u2h(__builtin_amdgcn_readfirstlane(hdr[1624 + c * 25 + k]));
    h2v dbch = u2h(__builtin_amdgcn_readfirstlane(hdr[2324 + c]));

    uint2 mu0, mu1, mu2, mu3, mu4;
    PRE(0, 0); PRE(1, 1); PRE(2, 2); PRE(3, 3);

    __syncthreads();

    h2v W00,W01,W02,W03,W04,W05, W10,W11,W12,W13,W14,W15,
        W20,W21,W22,W23,W24,W25, W30,W31,W32,W33,W34,W35,
        W40,W41,W42,W43,W44,W45;

    LDROW(0, lbase + 0); LDROW(1, lbase + 1); LDROW(2, lbase + 2); LDROW(3, lbase + 3);
    LDROW(4, lbase + 4);  PRE(4, 4);  CROW2(0, 0, 0,1,2,3,4);
    LDROW(0, lbase + 5);  PRE(0, 5);  CROW2(1, 1, 1,2,3,4,0);
    LDROW(1, lbase + 6);  PRE(1, 6);  CROW2(2, 2, 2,3,4,0,1);
    LDROW(2, lbase + 7);  PRE(2, 7);  CROW2(3, 3, 3,4,0,1,2);
    LDROW(3, lbase + 8);              CROW2(4, 4, 4,0,1,2,3);
    LDROW(4, lbase + 9);              CROW2(5, 0, 0,1,2,3,4);
    LDROW(0, lbase + 10);             CROW2(6, 1, 1,2,3,4,0);
    LDROW(1, lbase + 11);             CROW2(7, 2, 2,3,4,0,1);
}

// ---------------- K34: fused A_op-residual + A_pinv + output; [h][c][w] phm/php ----------------
__global__ __launch_bounds__(256, 8) void k34_out(
    const float* __restrict__ y, const float* __restrict__ x_pre,
    const unsigned short* __restrict__ phm, const unsigned short* __restrict__ php,
    const unsigned int* __restrict__ hdr, const float* __restrict__ delta,
    float* __restrict__ out)
{
    __shared__ float temp[312];

    int tid = threadIdx.x;
    int b = blockIdx.x >> 8;
    int h = blockIdx.x & 255;
    const float* alpha = (const float*)(hdr + 2352);
    size_t rowbase = ((size_t)b * NC) * HW + (size_t)h * 256;    // planar x_pre/out
    size_t pbase   = ((size_t)(b * 256 + h) * 28) << 8;          // [h][c][w] phm/php
    const float* yr = y + ((size_t)b * 256 + h) * COLW;

    // pass 1: thread = column pair (c0, c0+1), c0 even; 155 active threads
    if (tid < 155) {
        int c0 = tid * 2;
        float2 yv = *reinterpret_cast<const float2*>(yr + c0);
        float acc0 = yv.x, acc1 = yv.y;
        float2 xs0,xs1,xs2,xs3,xs4,xs5,xs6;
        unsigned int es0,es1,es2,es3,es4,es5,es6;

#define ISSUE(J, I) do { \
        int cs_ = c0 - 2 * (I); \
        bool v_ = ((unsigned)cs_) < 256u; \
        int cso_ = v_ ? cs_ : 0; \
        gl_f32x2(xs##J, x_pre + rowbase + (size_t)(I) * HW + cso_); \
        gl_b32(es##J, phm + pbase + ((I) << 8) + cso_); \
    } while(0)
#define CONSUME(J, I) do { \
        int cs_ = c0 - 2 * (I); \
        bool v_ = ((unsigned)cs_) < 256u; \
        acc0 -= v_ ? xs##J.x * h2f_lo(es##J) : 0.f; \
        acc1 -= v_ ? xs##J.y * h2f_hi(es##J) : 0.f; \
    } while(0)
#define GRP(B0) \
        ISSUE(0,(B0)+0); ISSUE(1,(B0)+1); ISSUE(2,(B0)+2); ISSUE(3,(B0)+3); \
        ISSUE(4,(B0)+4); ISSUE(5,(B0)+5); ISSUE(6,(B0)+6); \
        wait_vm0(); \
        CONSUME(0,(B0)+0); CONSUME(1,(B0)+1); CONSUME(2,(B0)+2); CONSUME(3,(B0)+3); \
        CONSUME(4,(B0)+4); CONSUME(5,(B0)+5); CONSUME(6,(B0)+6);

        GRP(0) GRP(7) GRP(14) GRP(21)
#undef GRP
#undef CONSUME
#undef ISSUE

        float2 av = *reinterpret_cast<const float2*>(alpha + c0);
        *reinterpret_cast<float2*>(&temp[c0]) = make_float2(acc0 * av.x, acc1 * av.y);
    }
    __syncthreads();

    // pass 2: thread = (w-pair, i-half); 14 taps each, 2 batches of 7
    float d = delta[0];
    int wp = (tid & 127) * 2;
    int ihalf = tid >> 7;
#pragma unroll
    for (int g = 0; g < 2; g++) {
        int i0 = ihalf * 14 + g * 7;
        float2 xp0,xp1,xp2,xp3,xp4,xp5,xp6;
        unsigned int ep0,ep1,ep2,ep3,ep4,ep5,ep6;
#define ISSUE2(J) do { \
        gl_f32x2(xp##J, x_pre + rowbase + (size_t)(i0 + (J)) * HW + wp); \
        gl_b32(ep##J, php + pbase + ((size_t)(i0 + (J)) << 8) + wp); \
    } while(0)
#define STORE2(J) do { \
        int i_ = i0 + (J); \
        size_t off_ = rowbase + (size_t)i_ * HW + wp; \
        float2 tv = *reinterpret_cast<const float2*>(&temp[wp + 2 * i_]); \
        float2 o2; \
        o2.x = fmaf(d * tv.x, h2f_lo(ep##J), xp##J.x); \
        o2.y = fmaf(d * tv.y, h2f_hi(ep##J), xp##J.y); \
        *reinterpret_cast<float2*>(out + off_) = o2; \
    } while(0)
        ISSUE2(0); ISSUE2(1); ISSUE2(2); ISSUE2(3); ISSUE2(4); ISSUE2(5); ISSUE2(6);
        wait_vm0();
        STORE2(0); STORE2(1); STORE2(2); STORE2(3); STORE2(4); STORE2(5); STORE2(6);
#undef ISSUE2
#undef STORE2
    }
}

// ---------------- launch ----------------
extern "C" void kernel_launch(void* const* d_in, const int* in_sizes, int n_in,
                              void* d_out, int out_size, void* d_ws, size_t ws_size,
                              hipStream_t stream)
{
    const float* y     = (const float*)d_in[0];
    const float* Phi   = (const float*)d_in[1];
    const float* x_pre = (const float*)d_in[2];
    const float* delta = (const float*)d_in[3];
    const float* mm_w1 = (const float*)d_in[4];
    const float* mm_b1 = (const float*)d_in[5];
    const float* mm_w2 = (const float*)d_in[6];
    const float* mm_b2 = (const float*)d_in[7];
    const float* mm_dw = (const float*)d_in[8];
    const float* mm_db = (const float*)d_in[9];
    const float* pv_w1 = (const float*)d_in[10];
    const float* pv_b1 = (const float*)d_in[11];
    const float* pv_w2 = (const float*)d_in[12];
    const float* pv_b2 = (const float*)d_in[13];
    const float* pv_dw = (const float*)d_in[14];
    const float* pv_db = (const float*)d_in[15];
    float* out = (float*)d_out;

    char* ws = (char*)d_ws;
    const size_t A = (size_t)BATCH * NC * HW * 4;   // 117,440,512 B
    unsigned int*   hdr   = (unsigned int*)ws;
    unsigned int*   t_pk  = (unsigned int*)(ws + HDR_BYTES);
    unsigned int*   m1_pk = (unsigned int*)(ws + HDR_BYTES + A);
    unsigned short* phm   = (unsigned short*)(ws + HDR_BYTES + 2 * A);
    unsigned short* php   = (unsigned short*)(ws + HDR_BYTES + 2 * A + A / 2);

    k0_prep<<<1, 256, 0, stream>>>(mm_w1, pv_w1, mm_w2, pv_w2,
                                   mm_b1, pv_b1, mm_b2, pv_b2,
                                   mm_dw, pv_dw, mm_db, pv_db, hdr);
    k1_conv1x1<<<2048, 256, 0, stream>>>(Phi, hdr, t_pk, m1_pk);
    k2_attn<<<BATCH * NC * 16, 256, 0, stream>>>(t_pk, m1_pk, hdr, phm, php);
    k34_out<<<BATCH * 256, 256, 0, stream>>>(y, x_pre, phm, php, hdr, delta, out);
}

// Round 24
// 224.151 us; speedup vs baseline: 1.0349x; 1.0349x over previous
//
#include <hip/hip_runtime.h>
#include <hip/hip_bf16.h>
#include <cstdint>

#define NC 28
#define HW 65536   // 256*256
#define ROWW 256
#define COLW 310
#define BATCH 16

typedef __hip_bfloat16 bf16;
typedef _Float16 h2v __attribute__((ext_vector_type(2)));

__device__ __forceinline__ unsigned int pkh(float lo, float hi) {
    auto h = __builtin_amdgcn_cvt_pkrtz(lo, hi);
    return __builtin_bit_cast(unsigned int, h);
}
__device__ __forceinline__ h2v u2h(unsigned int u) { return __builtin_bit_cast(h2v, u); }
__device__ __forceinline__ unsigned int h2u(h2v h) { return __builtin_bit_cast(unsigned int, h); }
__device__ __forceinline__ float h2f_lo(unsigned int u) {
    return (float)__builtin_bit_cast(_Float16, (unsigned short)(u & 0xffffu));
}
__device__ __forceinline__ float h2f_hi(unsigned int u) {
    return (float)__builtin_bit_cast(_Float16, (unsigned short)(u >> 16));
}
// forced async global loads (compiler cannot sink an asm volatile)
__device__ __forceinline__ void gl_f32x2(float2& d, const float* p) {
    asm volatile("global_load_dwordx2 %0, %1, off" : "=v"(d) : "v"(p));
}
__device__ __forceinline__ void gl_b32(unsigned int& d, const unsigned short* p) {
    asm volatile("global_load_dword %0, %1, off" : "=v"(d) : "v"(p));
}
__device__ __forceinline__ void wait_vm0() {
    asm volatile("s_waitcnt vmcnt(0)" ::: "memory");
    __builtin_amdgcn_sched_barrier(0);   // rule #18
}

#define REP28A(X) X(0) X(1) X(2) X(3) X(4) X(5) X(6) X(7) X(8) X(9) X(10) X(11) X(12) X(13) \
                  X(14) X(15) X(16) X(17) X(18) X(19) X(20) X(21) X(22) X(23) X(24) X(25) X(26) X(27)

// hdr layout (uint words):
//   [0..783]     w1h[c*28+o]  f16 pair (mm,pv)  (transposed)
//   [784..1567]  w2h[o*28+m]
//   [1568..1595] b1h[o]
//   [1596..1623] b2h[o]
//   [1624..2323] dwh[c*25+k]
//   [2324..2351] dbh[c]
//   [2352..2661] alpha[col] (float bits)
#define HDR_BYTES 16384

// ---------------- K0: prep ----------------
__global__ void k0_prep(const float* __restrict__ w1mm, const float* __restrict__ w1pv,
                        const float* __restrict__ w2mm, const float* __restrict__ w2pv,
                        const float* __restrict__ b1mm, const float* __restrict__ b1pv,
                        const float* __restrict__ b2mm, const float* __restrict__ b2pv,
                        const float* __restrict__ dwm,  const float* __restrict__ dwp,
                        const float* __restrict__ dbm,  const float* __restrict__ dbp,
                        unsigned int* __restrict__ hdr)
{
    int t = threadIdx.x;
    for (int e = t; e < 784; e += 256) {
        int c = e / 28, o = e - c * 28;
        hdr[e]       = pkh(w1mm[o * 28 + c], w1pv[o * 28 + c]);
        hdr[784 + e] = pkh(w2mm[e], w2pv[e]);
    }
    if (t < 28) {
        hdr[1568 + t] = pkh(b1mm[t], b1pv[t]);
        hdr[1596 + t] = pkh(b2mm[t], b2pv[t]);
        hdr[2324 + t] = pkh(dbm[t], dbp[t]);
    }
    for (int e = t; e < 700; e += 256)
        hdr[1624 + e] = pkh(dwm[e], dwp[e]);
    float* alpha = (float*)(hdr + 2352);
    for (int col = t; col < COLW; col += 256) {
        int imin = (col > 255) ? ((col - 254) >> 1) : 0;
        int imax = min(27, col >> 1);
        alpha[col] = 1.0f / (float)(imax - imin + 1);
    }
}

// ---------------- K1: conv1x1 x2; native h2v FMA, 9-slot rotating dwordx2 prefetch ----------------
__global__ __launch_bounds__(256, 4) void k1_conv1x1(
    const float* __restrict__ Phi, const unsigned int* __restrict__ hdr,
    unsigned int* __restrict__ t_pk, unsigned int* __restrict__ m1_pk)
{
    int idx = blockIdx.x * 256 + threadIdx.x;   // pixel-pair index
    int b   = idx >> 15;                        // 32768 pairs per batch
    int hw2 = (idx & 32767) << 1;
    const float* phi = Phi + (size_t)b * NC * HW + hw2;
    const unsigned int* w1h = hdr;              // [c*28+o]
    const unsigned int* w2h = hdr + 784;        // [o*28+m]
    const unsigned int* b1h = hdr + 1568;
    const unsigned int* b2h = hdr + 1596;

#define DECL_M(i) h2v MA##i = u2h(b1h[i]), MB##i = MA##i;
    REP28A(DECL_M)
#undef DECL_M

    float2 PQ0, PQ1, PQ2, PQ3, PQ4, PQ5, PQ6, PQ7, PQ8;
#define GLX2(D, C) asm volatile("global_load_dwordx2 %0, %1, off" : "=v"(D) : "v"(phi + (size_t)(C) * HW))
#define VMW(N) do { asm volatile("s_waitcnt vmcnt(" #N ")" ::: "memory"); \
                    __builtin_amdgcn_sched_barrier(0); } while(0)
#define FMA_M(i) MA##i = wr1_[i] * pa + MA##i; MB##i = wr1_[i] * pb + MB##i;
#define K1CONS(C, S) do { \
    h2v pa = u2h(pkh(PQ##S.x, PQ##S.x)); \
    h2v pb = u2h(pkh(PQ##S.y, PQ##S.y)); \
    const h2v* wr1_ = (const h2v*)(w1h + (C) * NC); \
    REP28A(FMA_M) \
} while(0)

    GLX2(PQ0, 0); GLX2(PQ1, 1); GLX2(PQ2, 2); GLX2(PQ3, 3);
    GLX2(PQ4, 4); GLX2(PQ5, 5); GLX2(PQ6, 6); GLX2(PQ7, 7);
    GLX2(PQ8, 8);  VMW(8); K1CONS(0, 0);
    GLX2(PQ0, 9);  VMW(8); K1CONS(1, 1);
    GLX2(PQ1, 10); VMW(8); K1CONS(2, 2);
    GLX2(PQ2, 11); VMW(8); K1CONS(3, 3);
    GLX2(PQ3, 12); VMW(8); K1CONS(4, 4);
    GLX2(PQ4, 13); VMW(8); K1CONS(5, 5);
    GLX2(PQ5, 14); VMW(8); K1CONS(6, 6);
    GLX2(PQ6, 15); VMW(8); K1CONS(7, 7);
    GLX2(PQ7, 16); VMW(8); K1CONS(8, 8);
    GLX2(PQ8, 17); VMW(8); K1CONS(9, 0);
    GLX2(PQ0, 18); VMW(8); K1CONS(10, 1);
    GLX2(PQ1, 19); VMW(8); K1CONS(11, 2);
    GLX2(PQ2, 20); VMW(8); K1CONS(12, 3);
    GLX2(PQ3, 21); VMW(8); K1CONS(13, 4);
    GLX2(PQ4, 22); VMW(8); K1CONS(14, 5);
    GLX2(PQ5, 23); VMW(8); K1CONS(15, 6);
    GLX2(PQ6, 24); VMW(8); K1CONS(16, 7);
    GLX2(PQ7, 25); VMW(8); K1CONS(17, 8);
    GLX2(PQ8, 26); VMW(8); K1CONS(18, 0);
    GLX2(PQ0, 27); VMW(8); K1CONS(19, 1);
    VMW(7); K1CONS(20, 2);
    VMW(6); K1CONS(21, 3);
    VMW(5); K1CONS(22, 4);
    VMW(4); K1CONS(23, 5);
    VMW(3); K1CONS(24, 6);
    VMW(2); K1CONS(25, 7);
    VMW(1); K1CONS(26, 8);
    VMW(0); K1CONS(27, 0);
#undef K1CONS
#undef FMA_M
#undef VMW
#undef GLX2

    size_t base = (size_t)b * NC * HW + hw2;
#define ST_M(i) *reinterpret_cast<uint2*>(m1_pk + base + (size_t)(i) * HW) = \
    make_uint2(h2u(MA##i), h2u(MB##i));
    REP28A(ST_M)
#undef ST_M

    for (int o = 0; o < NC; o++) {
        const h2v* wr2_ = (const h2v*)(w2h + o * NC);
        h2v Ta = u2h(b2h[o]), Tb = Ta;
#define FMA_T(i) Ta = wr2_[i] * MA##i + Ta; Tb = wr2_[i] * MB##i + Tb;
        REP28A(FMA_T)
#undef FMA_T
        *reinterpret_cast<uint2*>(t_pk + base + (size_t)o * HW) = make_uint2(h2u(Ta), h2u(Tb));
    }
}

// ---------------- K2: dwconv5 + sigmoid + emb + where; native h2v taps, LDS staging ----------------
#define TR 16
#define LROW 264   // words per LDS row; interior at [4..259], pads [2,3] and [260,261]

#define LDROW(S, LR) do { \
    const uint2* rp_ = reinterpret_cast<const uint2*>(&st[(LR) * LROW + 2 + cc]); \
    uint2 a_ = rp_[0], b_ = rp_[1], c_ = rp_[2]; \
    W##S##0 = u2h(a_.x); W##S##1 = u2h(a_.y); W##S##2 = u2h(b_.x); \
    W##S##3 = u2h(b_.y); W##S##4 = u2h(c_.x); W##S##5 = u2h(c_.y); \
} while(0)

#define PRE(S, R) do { \
    size_t o_ = cbase + (size_t)(h0 + (R)) * 256 + cc; \
    mu##S = *reinterpret_cast<const uint2*>(m1_pk + o_); \
} while(0)

#define TAPR(S, B) \
    acc0 = wqh[(B)+0] * W##S##0 + acc0; acc1 = wqh[(B)+0] * W##S##1 + acc1; \
    acc0 = wqh[(B)+1] * W##S##1 + acc0; acc1 = wqh[(B)+1] * W##S##2 + acc1; \
    acc0 = wqh[(B)+2] * W##S##2 + acc0; acc1 = wqh[(B)+2] * W##S##3 + acc1; \
    acc0 = wqh[(B)+3] * W##S##3 + acc0; acc1 = wqh[(B)+3] * W##S##4 + acc1; \
    acc0 = wqh[(B)+4] * W##S##4 + acc0; acc1 = wqh[(B)+4] * W##S##5 + acc1;

#define CROW2(R, PS, S0,S1,S2,S3,S4) do { \
    h2v acc0 = dbch, acc1 = dbch; \
    TAPR(S0, 0) TAPR(S1, 5) TAPR(S2, 10) TAPR(S3, 15) TAPR(S4, 20) \
    float am0 = (float)acc0.x, ap0 = (float)acc0.y; \
    float am1 = (float)acc1.x, ap1 = (float)acc1.y; \
    float atm0 = __builtin_amdgcn_rcpf(1.f + __expf(-am0)); \
    float atp0 = __builtin_amdgcn_rcpf(1.f + __expf(-ap0)); \
    float atm1 = __builtin_amdgcn_rcpf(1.f + __expf(-am1)); \
    float atp1 = __builtin_amdgcn_rcpf(1.f + __expf(-ap1)); \
    float m1m0 = h2f_lo(mu##PS.x), m1p0 = h2f_hi(mu##PS.x); \
    float m1m1 = h2f_lo(mu##PS.y), m1p1 = h2f_hi(mu##PS.y); \
    float em0 = fmaf(m1m0, atm0, m1m0); \
    float ep0 = fmaf(m1p0, atp0, m1p0); \
    float em1 = fmaf(m1m1, atm1, m1m1); \
    float ep1 = fmaf(m1p1, atp1, m1p1); \
    if (em0 == 0.f) em0 = 1e-6f; \
    if (ep0 == 0.f) ep0 = 1e-6f; \
    if (em1 == 0.f) em1 = 1e-6f; \
    if (ep1 == 0.f) ep1 = 1e-6f; \
    size_t off_ = cbase + (size_t)(h0 + (R)) * 256 + cc; \
    *reinterpret_cast<unsigned int*>(phm + off_) = pkh(em0, em1); \
    *reinterpret_cast<unsigned int*>(php + off_) = pkh(ep0, ep1); \
} while(0)

__global__ __launch_bounds__(256, 4) void k2_attn(
    const unsigned int* __restrict__ t_pk, const unsigned int* __restrict__ m1_pk,
    const unsigned int* __restrict__ hdr,
    unsigned short* __restrict__ phm, unsigned short* __restrict__ php)
{
    __shared__ unsigned int st[(TR + 4) * LROW];   // 21,120 B

    int bid = blockIdx.x;
    int rt = bid & 15;
    int c  = (bid >> 4) % NC;
    int b  = (bid >> 4) / NC;
    int r0 = rt * TR;
    size_t cbase = ((size_t)b * NC + c) * HW;
    int tid = threadIdx.x;
    int lane = tid & 63;
    int wv = tid >> 6;
    int cc = (tid & 127) * 2;        // column pair base
    int half = tid >> 7;             // 0: rows 0..7, 1: rows 8..15
    int lbase = half * 8;
    int h0 = r0 + lbase;

    if (tid < 80) {
        int rr = tid >> 2, jj = tid & 3;
        st[rr * LROW + ((jj < 2) ? 2 + jj : 258 + jj)] = 0u;
    }

#pragma unroll
    for (int j = 0; j < 5; j++) {
        int r = wv * 5 + j;
        int gr = r0 - 2 + r;
        if (gr >= 0 && gr < 256) {
            const unsigned int* gsrc = t_pk + cbase + (size_t)gr * 256 + lane * 4;
            __builtin_amdgcn_global_load_lds(
                (const __attribute__((address_space(1))) unsigned int*)gsrc,
                (__attribute__((address_space(3))) unsigned int*)&st[r * LROW + 4],
                16, 0, 0);
        } else {
            st[r * LROW + 4 + lane]       = 0u;
            st[r * LROW + 4 + 64 + lane]  = 0u;
            st[r * LROW + 4 + 128 + lane] = 0u;
            st[r * LROW + 4 + 192 + lane] = 0u;
        }
    }

    h2v wqh[25];
#pragma unroll
    for (int k = 0; k < 25; k++)
        wqh[k] = u2h(__builtin_amdgcn_readfirstlane(hdr[1624 + c * 25 + k]));
    h2v dbch = u2h(__builtin_amdgcn_readfirstlane(hdr[2324 + c]));

    uint2 mu0, mu1, mu2, mu3, mu4;
    PRE(0, 0); PRE(1, 1); PRE(2, 2); PRE(3, 3);

    __syncthreads();

    h2v W00,W01,W02,W03,W04,W05, W10,W11,W12,W13,W14,W15,
        W20,W21,W22,W23,W24,W25, W30,W31,W32,W33,W34,W35,
        W40,W41,W42,W43,W44,W45;

    LDROW(0, lbase + 0); LDROW(1, lbase + 1); LDROW(2, lbase + 2); LDROW(3, lbase + 3);
    LDROW(4, lbase + 4);  PRE(4, 4);  CROW2(0, 0, 0,1,2,3,4);
    LDROW(0, lbase + 5);  PRE(0, 5);  CROW2(1, 1, 1,2,3,4,0);
    LDROW(1, lbase + 6);  PRE(1, 6);  CROW2(2, 2, 2,3,4,0,1);
    LDROW(2, lbase + 7);  PRE(2, 7);  CROW2(3, 3, 3,4,0,1,2);
    LDROW(3, lbase + 8);              CROW2(4, 4, 4,0,1,2,3);
    LDROW(4, lbase + 9);              CROW2(5, 0, 0,1,2,3,4);
    LDROW(0, lbase + 10);             CROW2(6, 1, 1,2,3,4,0);
    LDROW(1, lbase + 11);             CROW2(7, 2, 2,3,4,0,1);
}

// ---------------- K34: fused A_op-residual + A_pinv + output; x_pre cached in LDS ----------------
__global__ __launch_bounds__(256, 5) void k34_out(
    const float* __restrict__ y, const float* __restrict__ x_pre,
    const unsigned short* __restrict__ phm, const unsigned short* __restrict__ php,
    const unsigned int* __restrict__ hdr, const float* __restrict__ delta,
    float* __restrict__ out)
{
    __shared__ float temp[312];
    __shared__ float xls[NC][256];   // 28 KB: x_pre row cache, filled by pass 1

    int tid = threadIdx.x;
    int b = blockIdx.x >> 8;
    int h = blockIdx.x & 255;
    const float* alpha = (const float*)(hdr + 2352);
    size_t rowbase = ((size_t)b * NC) * HW + (size_t)h * 256;   // + i*HW + w
    const float* yr = y + ((size_t)b * 256 + h) * COLW;

    // pass 1: thread = column pair (c0, c0+1), c0 even; 155 active threads.
    // Stashes every valid x_pre element into LDS (col = cs+2i is a bijection onto [0,256) per i).
    if (tid < 155) {
        int c0 = tid * 2;
        float2 yv = *reinterpret_cast<const float2*>(yr + c0);
        float acc0 = yv.x, acc1 = yv.y;
        float2 xs0,xs1,xs2,xs3,xs4,xs5,xs6;
        unsigned int es0,es1,es2,es3,es4,es5,es6;

#define ISSUE(J, I) do { \
        int cs_ = c0 - 2 * (I); \
        bool v_ = ((unsigned)cs_) < 256u; \
        size_t off_ = rowbase + (size_t)(I) * HW + (v_ ? cs_ : 0); \
        gl_f32x2(xs##J, x_pre + off_); \
        gl_b32(es##J, phm + off_); \
    } while(0)
#define CONSUME(J, I) do { \
        int cs_ = c0 - 2 * (I); \
        bool v_ = ((unsigned)cs_) < 256u; \
        if (v_) *reinterpret_cast<float2*>(&xls[(I)][cs_]) = xs##J; \
        acc0 -= v_ ? xs##J.x * h2f_lo(es##J) : 0.f; \
        acc1 -= v_ ? xs##J.y * h2f_hi(es##J) : 0.f; \
    } while(0)
#define GRP(B0) \
        ISSUE(0,(B0)+0); ISSUE(1,(B0)+1); ISSUE(2,(B0)+2); ISSUE(3,(B0)+3); \
        ISSUE(4,(B0)+4); ISSUE(5,(B0)+5); ISSUE(6,(B0)+6); \
        wait_vm0(); \
        CONSUME(0,(B0)+0); CONSUME(1,(B0)+1); CONSUME(2,(B0)+2); CONSUME(3,(B0)+3); \
        CONSUME(4,(B0)+4); CONSUME(5,(B0)+5); CONSUME(6,(B0)+6);

        GRP(0) GRP(7) GRP(14) GRP(21)
#undef GRP
#undef CONSUME
#undef ISSUE

        float2 av = *reinterpret_cast<const float2*>(alpha + c0);
        *reinterpret_cast<float2*>(&temp[c0]) = make_float2(acc0 * av.x, acc1 * av.y);
    }
    __syncthreads();

    // pass 2: thread = (w-pair, i-half); x_pre from LDS, php batched from global
    float d = delta[0];
    int wp = (tid & 127) * 2;
    int ihalf = tid >> 7;
#pragma unroll
    for (int g = 0; g < 2; g++) {
        int i0 = ihalf * 14 + g * 7;
        unsigned int ep0,ep1,ep2,ep3,ep4,ep5,ep6;
#define ISSUE2(J) gl_b32(ep##J, php + rowbase + (size_t)(i0 + (J)) * HW + wp)
#define STORE2(J) do { \
        int i_ = i0 + (J); \
        size_t off_ = rowbase + (size_t)i_ * HW + wp; \
        float2 tv = *reinterpret_cast<const float2*>(&temp[wp + 2 * i_]); \
        float2 xv = *reinterpret_cast<const float2*>(&xls[i_][wp]); \
        float2 o2; \
        o2.x = fmaf(d * tv.x, h2f_lo(ep##J), xv.x); \
        o2.y = fmaf(d * tv.y, h2f_hi(ep##J), xv.y); \
        *reinterpret_cast<float2*>(out + off_) = o2; \
    } while(0)
        ISSUE2(0); ISSUE2(1); ISSUE2(2); ISSUE2(3); ISSUE2(4); ISSUE2(5); ISSUE2(6);
        wait_vm0();
        STORE2(0); STORE2(1); STORE2(2); STORE2(3); STORE2(4); STORE2(5); STORE2(6);
#undef ISSUE2
#undef STORE2
    }
}

// ---------------- launch ----------------
extern "C" void kernel_launch(void* const* d_in, const int* in_sizes, int n_in,
                              void* d_out, int out_size, void* d_ws, size_t ws_size,
                              hipStream_t stream)
{
    const float* y     = (const float*)d_in[0];
    const float* Phi   = (const float*)d_in[1];
    const float* x_pre = (const float*)d_in[2];
    const float* delta = (const float*)d_in[3];
    const float* mm_w1 = (const float*)d_in[4];
    const float* mm_b1 = (const float*)d_in[5];
    const float* mm_w2 = (const float*)d_in[6];
    const float* mm_b2 = (const float*)d_in[7];
    const float* mm_dw = (const float*)d_in[8];
    const float* mm_db = (const float*)d_in[9];
    const float* pv_w1 = (const float*)d_in[10];
    const float* pv_b1 = (const float*)d_in[11];
    const float* pv_w2 = (const float*)d_in[12];
    const float* pv_b2 = (const float*)d_in[13];
    const float* pv_dw = (const float*)d_in[14];
    const float* pv_db = (const float*)d_in[15];
    float* out = (float*)d_out;

    char* ws = (char*)d_ws;
    const size_t A = (size_t)BATCH * NC * HW * 4;   // 117,440,512 B
    unsigned int*   hdr   = (unsigned int*)ws;
    unsigned int*   t_pk  = (unsigned int*)(ws + HDR_BYTES);
    unsigned int*   m1_pk = (unsigned int*)(ws + HDR_BYTES + A);
    unsigned short* phm   = (unsigned short*)(ws + HDR_BYTES + 2 * A);
    unsigned short* php   = (unsigned short*)(ws + HDR_BYTES + 2 * A + A / 2);

    k0_prep<<<1, 256, 0, stream>>>(mm_w1, pv_w1, mm_w2, pv_w2,
                                   mm_b1, pv_b1, mm_b2, pv_b2,
                                   mm_dw, pv_dw, mm_db, pv_db, hdr);
    k1_conv1x1<<<2048, 256, 0, stream>>>(Phi, hdr, t_pk, m1_pk);
    k2_attn<<<BATCH * NC * 16, 256, 0, stream>>>(t_pk, m1_pk, hdr, phm, php);
    k34_out<<<BATCH * 256, 256, 0, stream>>>(y, x_pre, phm, php, hdr, delta, out);
}